// Round 7
// baseline (303.915 us; speedup 1.0000x reference)
//
#include <hip/hip_runtime.h>
#include <hip/hip_fp16.h>

typedef _Float16 f16;
typedef f16 f16x4 __attribute__((ext_vector_type(4)));
typedef f16 f16x8 __attribute__((ext_vector_type(8)));
typedef float f32x4 __attribute__((ext_vector_type(4)));

#define NTOK 32768   // B*S
#define KDIM 512
#define SLEN 4096
#define BATCH 8
#define WSZ  262144  // 512*512

#define GLOAD_LDS16(g, l) __builtin_amdgcn_global_load_lds(                 \
    (const __attribute__((address_space(1))) void*)(g),                     \
    (__attribute__((address_space(3))) void*)(l), 16, 0, 0)

__device__ __forceinline__ float fast_tanh(float x) {
    float ax = fabsf(x);
    float t = __expf(-2.0f * ax);
    float r = (1.0f - t) / (1.0f + t);
    return copysignf(r, x);
}

// =====================  fused 4-phase chain  =====================
// Each block owns 128 tokens. LDS holds h (or X) as [token 128][feature 512] f16,
// XOR-swizzled in 16B chunks: element (m, f) at m*512 + ((f>>3 ^ (m&7))<<3) + (f&7).
// Phases compute D^T[feature][token] = mfma(W_rowfrag, h_frag).
// kt-loop is software-pipelined 2 deep (prefetch wf/hf for kt+1 during kt's MFMAs).
__global__ __launch_bounds__(512, 2)
void chain_kernel(const float* __restrict__ xs,
                  const f16*  __restrict__ Wp,    // [4][512*512] f16 row-major [j][k]
                  const float* __restrict__ bias, // [4][512] fp32
                  float* __restrict__ out)        // y2 [S,B,512] then hs [8*512]
{
    __shared__ f16 hbuf[128][512];   // 128 KB

    const int tid  = threadIdx.x;
    const int bid  = blockIdx.x;
    const int n0   = bid * 128;
    const int lane = tid & 63;
    const int wave = tid >> 6;       // 0..7: wave owns features [wave*64, +64)
    const int fr   = lane & 15;      // token within 16-tile (D^T col)
    const int q    = lane >> 4;      // 0..3
    const int j0w  = wave * 64;

    // ---- stage X tile: fp32 -> f16 into hbuf (swizzled) ----
    {
        const int tk = tid >> 2;                 // 0..127
        const int cq = tid & 3;                  // 0..3
        const float* __restrict__ src = &xs[(size_t)(n0 + tk) * KDIM];
        #pragma unroll
        for (int kt = 0; kt < 16; ++kt) {
            const int k = kt * 32 + cq * 8;
            const float4 v0 = *(const float4*)&src[k];
            const float4 v1 = *(const float4*)&src[k + 4];
            f16x8 h;
            h[0]=(f16)v0.x; h[1]=(f16)v0.y; h[2]=(f16)v0.z; h[3]=(f16)v0.w;
            h[4]=(f16)v1.x; h[5]=(f16)v1.y; h[6]=(f16)v1.z; h[7]=(f16)v1.w;
            const int c = (k >> 3) ^ (tk & 7);
            *(f16x8*)&hbuf[tk][c << 3] = h;
        }
    }

    // hoisted fragment addresses
    const f16* __restrict__ hrow[8];
    int hswz[8];
    #pragma unroll
    for (int mt = 0; mt < 8; ++mt) {
        const int m = mt * 16 + fr;
        hrow[mt] = &hbuf[m][0];
        hswz[mt] = m & 7;
    }

    f32x4 acc[4][8];   // [jt][mt] : 128 AGPRs

    for (int ph = 0; ph < 4; ++ph) {
        const f16*   __restrict__ wp = Wp + (size_t)ph * WSZ;
        const float* __restrict__ bp = bias + ph * KDIM;

        const f16* __restrict__ wrow[4];
        #pragma unroll
        for (int jt = 0; jt < 4; ++jt)
            wrow[jt] = &wp[(size_t)(j0w + jt * 16 + fr) * KDIM + q * 8];

        f32x4 bv[4];
        #pragma unroll
        for (int jt = 0; jt < 4; ++jt)
            bv[jt] = *(const f32x4*)&bp[j0w + jt * 16 + q * 4];
        #pragma unroll
        for (int jt = 0; jt < 4; ++jt)
            #pragma unroll
            for (int mt = 0; mt < 8; ++mt)
                acc[jt][mt] = bv[jt];

        __syncthreads();   // previous phase's h writes (or X staging) visible

        // hs_final: blocks holding token s==4095 (bid = 32b+31, local token 127)
        if (ph == 3 && (bid & 31) == 31) {
            const int f = tid;                      // feature 0..511
            const int c = (f >> 3) ^ 7;             // m=127 -> m&7 = 7
            out[(size_t)SLEN * BATCH * KDIM + (size_t)(bid >> 5) * KDIM + f] =
                (float)hbuf[127][(c << 3) + (f & 7)];
        }

        // ---- software-pipelined K loop ----
        f16x8 wf[2][4], hf[2][8];
        #pragma unroll
        for (int jt = 0; jt < 4; ++jt)
            wf[0][jt] = *(const f16x8*)&wrow[jt][0];
        #pragma unroll
        for (int mt = 0; mt < 8; ++mt)
            hf[0][mt] = *(const f16x8*)&hrow[mt][(q ^ hswz[mt]) << 3];

        #pragma unroll
        for (int kt = 0; kt < 16; ++kt) {
            const int cur = kt & 1, nxt = cur ^ 1;
            if (kt < 15) {
                #pragma unroll
                for (int jt = 0; jt < 4; ++jt)
                    wf[nxt][jt] = *(const f16x8*)&wrow[jt][(kt + 1) * 32];
                #pragma unroll
                for (int mt = 0; mt < 8; ++mt)
                    hf[nxt][mt] = *(const f16x8*)
                        &hrow[mt][((((kt + 1) * 4 + q) ^ hswz[mt])) << 3];
            }
            #pragma unroll
            for (int jt = 0; jt < 4; ++jt)
                #pragma unroll
                for (int mt = 0; mt < 8; ++mt)
                    acc[jt][mt] = __builtin_amdgcn_mfma_f32_16x16x32_f16(
                        wf[cur][jt], hf[cur][mt], acc[jt][mt], 0, 0, 0);
        }

        if (ph < 3) {
            __syncthreads();   // all reads done before in-place overwrite
            #pragma unroll
            for (int jt = 0; jt < 4; ++jt) {
                const int j0f  = j0w + jt * 16 + q * 4;   // 4 consecutive features
                const int c    = j0f >> 3;
                const int half = j0f & 7;                 // 0 or 4
                #pragma unroll
                for (int mt = 0; mt < 8; ++mt) {
                    const int m = mt * 16 + fr;
                    f16x4 hv;
                    hv[0] = (f16)fast_tanh(acc[jt][mt][0]);
                    hv[1] = (f16)fast_tanh(acc[jt][mt][1]);
                    hv[2] = (f16)fast_tanh(acc[jt][mt][2]);
                    hv[3] = (f16)fast_tanh(acc[jt][mt][3]);
                    *(f16x4*)&hbuf[m][((c ^ (m & 7)) << 3) + half] = hv;
                }
            }
        } else {
            // y2 -> global; D^T layout matches [s,b,j] with 4 consecutive j per lane
            #pragma unroll
            for (int jt = 0; jt < 4; ++jt) {
                const int j = j0w + jt * 16 + q * 4;
                #pragma unroll
                for (int mt = 0; mt < 8; ++mt) {
                    const int n  = n0 + mt * 16 + fr;
                    const int s  = n & (SLEN - 1);
                    const int bb = n >> 12;
                    *(f32x4*)&out[(size_t)(s * BATCH + bb) * KDIM + j] = acc[jt][mt];
                }
            }
        }
    }
}

// =====================  fold GEMM (proven path)  =====================
// C[n,j] = sum_k A[n,k]*W[j,k] + Cadd[n,j]  -> f16 out.  512x512, 16 blocks.
__global__ __launch_bounds__(256)
void gemm16_fold(const f16* __restrict__ A, const f16* __restrict__ W,
                 const float* __restrict__ Cadd, f16* __restrict__ Cp)
{
    __shared__ f16 A_s[128][64];
    __shared__ f16 B_s[128][64];

    const int tid = threadIdx.x;
    const int bid = blockIdx.x;
    const int n0 = (bid >> 2) * 128;
    const int j0 = (bid & 3) * 128;

    const int lane = tid & 63, wave = tid >> 6;
    const int wm = wave >> 1, wn = wave & 1;
    const int fr = lane & 15, q = lane >> 4, sw = fr & 7;
    const int ar8 = lane >> 3;
    const int ach = (lane & 7) ^ ar8;

    f32x4 acc[4][4] = {};

    for (int kt = 0; kt < 8; ++kt) {
        const int k0 = kt * 64;
        #pragma unroll
        for (int p = 0; p < 4; ++p) {
            const int r8 = wave * 32 + p * 8;
            GLOAD_LDS16(&A[(size_t)(n0 + r8 + ar8) * KDIM + k0 + (ach << 3)], &A_s[r8][0]);
            GLOAD_LDS16(&W[(size_t)(j0 + r8 + ar8) * KDIM + k0 + (ach << 3)], &B_s[r8][0]);
        }
        __syncthreads();
        #pragma unroll
        for (int kc = 0; kc < 8; kc += 4) {
            f16x8 a[4], b[4];
            #pragma unroll
            for (int t = 0; t < 4; ++t)
                a[t] = *(const f16x8*)&A_s[wm * 64 + t * 16 + fr][((kc + q) ^ sw) << 3];
            #pragma unroll
            for (int t = 0; t < 4; ++t)
                b[t] = *(const f16x8*)&B_s[wn * 64 + t * 16 + fr][((kc + q) ^ sw) << 3];
            #pragma unroll
            for (int im = 0; im < 4; ++im)
                #pragma unroll
                for (int jn = 0; jn < 4; ++jn)
                    acc[im][jn] = __builtin_amdgcn_mfma_f32_16x16x32_f16(
                        a[im], b[jn], acc[im][jn], 0, 0, 0);
        }
        __syncthreads();
    }

    const int r0 = q * 4, c = fr;
    #pragma unroll
    for (int jn = 0; jn < 4; ++jn) {
        const int j = j0 + wn * 64 + jn * 16 + c;
        #pragma unroll
        for (int im = 0; im < 4; ++im)
            #pragma unroll
            for (int r = 0; r < 4; ++r) {
                const int n = n0 + wm * 64 + im * 16 + r0 + r;
                Cp[(size_t)n * KDIM + j] =
                    (f16)(acc[im][jn][r] + Cadd[(size_t)n * KDIM + j]);
            }
    }
}

// =====================  prep: all cvt/tcvt in one launch  =====================
__device__ __forceinline__ void cvt2048(const float* __restrict__ src, f16* __restrict__ dst, int t)
{
    const float4 v0 = *(const float4*)&src[(size_t)t * 8];
    const float4 v1 = *(const float4*)&src[(size_t)t * 8 + 4];
    f16x8 h;
    h[0]=(f16)v0.x; h[1]=(f16)v0.y; h[2]=(f16)v0.z; h[3]=(f16)v0.w;
    h[4]=(f16)v1.x; h[5]=(f16)v1.y; h[6]=(f16)v1.z; h[7]=(f16)v1.w;
    *(f16x8*)&dst[(size_t)t * 8] = h;
}

__device__ __forceinline__ void tcvt64(const float* __restrict__ in, f16* __restrict__ out, int b, int tid)
{
    __shared__ float t[64][65];
    const int c0 = (b & 7) * 64, r0 = (b >> 3) * 64;
    const int tr = tid >> 4;
    const int tc = (tid & 15) * 4;
    #pragma unroll
    for (int i = 0; i < 4; ++i) {
        const float4 v = *(const float4*)&in[(size_t)(r0 + tr + 16 * i) * 512 + c0 + tc];
        t[tr + 16 * i][tc + 0] = v.x; t[tr + 16 * i][tc + 1] = v.y;
        t[tr + 16 * i][tc + 2] = v.z; t[tr + 16 * i][tc + 3] = v.w;
    }
    __syncthreads();
    #pragma unroll
    for (int i = 0; i < 4; ++i) {
        const int cl = tr + 16 * i;
        f16x4 h;
        h[0] = (f16)t[tc + 0][cl]; h[1] = (f16)t[tc + 1][cl];
        h[2] = (f16)t[tc + 2][cl]; h[3] = (f16)t[tc + 3][cl];
        *(f16x4*)&out[(size_t)(c0 + cl) * 512 + r0 + tc] = h;
    }
}

__global__ __launch_bounds__(256)
void prep_cvt(const float* __restrict__ W_xh0, const float* __restrict__ W_xh_h,
              const float* __restrict__ W_hy_h, const float* __restrict__ W_hy0,
              f16* __restrict__ Wp, f16* __restrict__ w_xhh, f16* __restrict__ wt)
{
    const int b = blockIdx.x, tid = threadIdx.x;
    if (b < 128)      cvt2048(W_xh0,            Wp,             b * 256 + tid);
    else if (b < 384) cvt2048(W_xh_h,           w_xhh,          (b - 128) * 256 + tid);
    else if (b < 512) cvt2048(W_hy_h + WSZ,     Wp + 3 * WSZ,   (b - 384) * 256 + tid);
    else if (b < 576) tcvt64(W_hy0,  wt,        b - 512, tid);
    else              tcvt64(W_hy_h, wt + WSZ,  b - 576, tid);
}

// =====================  bias prep: bias[4][512]  =====================
__global__ __launch_bounds__(256)
void bias_prep(const float* __restrict__ b_xh0, const float* __restrict__ b_hh0,
               const float* __restrict__ W_xh_h, const float* __restrict__ b_xh_h,
               const float* __restrict__ b_hh_h, const float* __restrict__ b_hy0,
               const float* __restrict__ b_hy_h, float* __restrict__ bias)
{
    const int b = blockIdx.x;
    const int row = b >> 1;
    const int j = (b & 1) * 256 + threadIdx.x;
    float v;
    if (row == 0)      v = b_xh0[j] + b_hh0[j];
    else if (row == 3) v = b_hy_h[KDIM + j];
    else {
        const int li = row - 1;
        const float* __restrict__ W  = W_xh_h + (size_t)li * WSZ;
        const float* __restrict__ bh = li ? b_hy_h : b_hy0;   // b_hy of previous cell
        v = b_hh_h[li * KDIM + j] + b_xh_h[li * KDIM + j];
        for (int k = 0; k < 512; k += 4) {
            const float4 w  = *(const float4*)&W[(size_t)j * 512 + k];
            const float4 bb = *(const float4*)&bh[k];
            v += w.x * bb.x + w.y * bb.y + w.z * bb.z + w.w * bb.w;
        }
    }
    bias[row * KDIM + j] = v;
}

extern "C" void kernel_launch(void* const* d_in, const int* in_sizes, int n_in,
                              void* d_out, int out_size, void* d_ws, size_t ws_size,
                              hipStream_t stream)
{
    (void)in_sizes; (void)n_in; (void)out_size; (void)ws_size;

    const float* xs     = (const float*)d_in[0];
    const float* W_xh0  = (const float*)d_in[1];
    const float* b_xh0  = (const float*)d_in[2];
    /* d_in[3] = W_hh0 unused (hs==0; only its bias matters) */
    const float* b_hh0  = (const float*)d_in[4];
    const float* W_hy0  = (const float*)d_in[5];
    const float* b_hy0  = (const float*)d_in[6];
    const float* W_xh_h = (const float*)d_in[7];
    const float* b_xh_h = (const float*)d_in[8];
    const float* W_hh_h = (const float*)d_in[9];
    const float* b_hh_h = (const float*)d_in[10];
    const float* W_hy_h = (const float*)d_in[11];
    const float* b_hy_h = (const float*)d_in[12];

    f16*   Wp    = (f16*)d_ws;                 // [4][WSZ] phase weights
    f16*   w_xhh = Wp + 4 * WSZ;               // fold inputs
    f16*   wt    = w_xhh + 2 * WSZ;            // W_hy0^T, W_hy_h[0]^T
    float* bias  = (float*)(wt + 2 * WSZ);     // [4][512]

    dim3 block(256);

    // prep: all conversions/transposes in one launch; biases in another
    prep_cvt<<<640, block, 0, stream>>>(W_xh0, W_xh_h, W_hy_h, W_hy0, Wp, w_xhh, wt);
    bias_prep<<<8, block, 0, stream>>>(b_xh0, b_hh0, W_xh_h, b_xh_h, b_hh_h,
                                       b_hy0, b_hy_h, bias);
    // W_eff[li] = W_hh_h[li] + W_xh_h[li] @ W_hy_prev  -> Wp[1+li]
    gemm16_fold<<<16, block, 0, stream>>>(w_xhh,       wt,       W_hh_h,       Wp + WSZ);
    gemm16_fold<<<16, block, 0, stream>>>(w_xhh + WSZ, wt + WSZ, W_hh_h + WSZ, Wp + 2 * WSZ);

    // fused chain: 256 blocks x 512 threads, 1 block/CU (LDS-capped)
    chain_kernel<<<256, dim3(512), 0, stream>>>(xs, Wp, bias, (float*)d_out);
}